// Round 9
// baseline (82.989 us; speedup 1.0000x reference)
//
#include <hip/hip_runtime.h>
#include <math.h>

// Problem constants: B=32, C=256, H=W=56, group=4, d=1
constexpr int B_  = 32;
constexpr int C_  = 256;
constexpr int G_  = 4;
constexpr int K_  = 64;
constexpr int P_  = 3136;        // 56*56
constexpr int NB_ = 29;
constexpr int BG_ = 128;         // B*G
constexpr int CP_ = C_ * P_;
constexpr int N_  = B_ * CP_;
constexpr int N4_ = N_ / 4;
constexpr float TWO_PI = 6.283185307179586f;

typedef float f4_t __attribute__((ext_vector_type(4)));   // native vec for nt-store

// Radial bin label in RAW (unshifted) coords, p = a*56 + b (symmetric in a,b).
__device__ __forceinline__ int lab_of(int p) {
    int h = p / 56, w = p - h * 56;
    int hh = ((h + 28) % 56) - 28;
    int ww = ((w + 28) % 56) - 28;
    int r2 = hh * hh + ww * ww;
    int rf = (int)sqrtf((float)r2);
    while ((rf + 1) * (rf + 1) <= r2) ++rf;
    while (rf * rf > r2) --rf;
    if (rf > 28) rf = 28;
    return rf;
}

// Ordered-uint key for float atomic min/max.
__device__ __forceinline__ unsigned fkey(float f) {
    unsigned u = __float_as_uint(f);
    return (u & 0x80000000u) ? ~u : (u | 0x80000000u);
}
__device__ __forceinline__ float fdec(unsigned k) {
    return (k & 0x80000000u) ? __uint_as_float(k ^ 0x80000000u) : __uint_as_float(~k);
}

// ---------------------------------------------------------------------------
// Radix 7x8 over a 56-line: n = 7*n2 + n1,
//   X[k] = sum_{n1<7} e^{s 2pi i n1 k/56} * T[n1][k&7],
//   T[n1][k0] = sum_{n2<8} x[7*n2+n1] e^{s 2pi i n2 k0/8}
// ---------------------------------------------------------------------------

// Kernel 1: fused comp + row-DFT (F1). One block per (bg, 4 rows).
// tmpF[bg][kw][h] = sum_w comp[bg][h][w] e^{-2pi i w kw/56}
// rblk==0 re-inits sums/mnmx (consumed only by later kernels).
__global__ __launch_bounds__(256) void comp_f1_kernel(const float* __restrict__ feature,
                                                      float2* __restrict__ tmpF,
                                                      float* __restrict__ sums,
                                                      unsigned* __restrict__ mnmx) {
    int blk = blockIdx.x, bg = blk / 14, rblk = blk - bg * 14, r0 = rblk * 4;
    int b = bg >> 2, g = bg & 3;
    int t = threadIdx.x;
    __shared__ float  sx[4][57];
    __shared__ float2 stw[56];
    if (rblk == 0) {
        if (t < NB_) sums[bg * NB_ + t] = 0.f;
        else if (t == NB_)     mnmx[bg * 2]     = 0xFFFFFFFFu;
        else if (t == NB_ + 1) mnmx[bg * 2 + 1] = 0u;
    }
    if (t < 56) { float a = -TWO_PI * (float)t / 56.f; stw[t] = make_float2(cosf(a), sinf(a)); }
    if (t < 224) {
        const float* base = feature + (b * C_ + g * K_) * P_ + r0 * 56 + t;
        float sum = 0.f, mx = -INFINITY;
#pragma unroll 8
        for (int k = 0; k < K_; ++k) {
            float v = base[k * P_];
            sum += v;
            mx = fmaxf(mx, v);
        }
        sx[t / 56][t % 56] = sum * (1.f / 64.f) + mx;
    }
    __syncthreads();
    if (t < 224) {
        int r = t & 3, k = t >> 2;
        float sr = 0.f, si = 0.f; int idx = 0;
        for (int j = 0; j < 56; ++j) {
            float v = sx[r][j];
            float2 tw = stw[idx];
            sr = fmaf(v, tw.x, sr); si = fmaf(v, tw.y, si);
            idx += k; if (idx >= 56) idx -= 56;
        }
        tmpF[bg * P_ + k * 56 + (r0 + r)] = make_float2(sr, si);
    }
}

// Kernel 2: F2 (col DFT over h, radix 7x8) + radial bin sums.
// Stores spec only for kw<=28 (Hermitian half; the rest is never read).
// Block 0 also computes inv_cnt (pure geometry).
__global__ __launch_bounds__(256) void f2_kernel(const float2* __restrict__ tmpF,
                                                 float2* __restrict__ specS,
                                                 float* __restrict__ sums,
                                                 float* __restrict__ inv_cnt) {
    int blk = blockIdx.x, bg = blk / 14, r0 = (blk - bg * 14) * 4;
    __shared__ float2 sx[4][57];
    __shared__ float2 sT[4][57];
    __shared__ float2 w56[56];
    __shared__ float2 w8[8];
    __shared__ float  sbins[NB_];
    int t = threadIdx.x;
    if (t < 56) { float a = -TWO_PI * (float)t / 56.f; w56[t] = make_float2(cosf(a), sinf(a)); }
    if (t < 8)  { float a = -TWO_PI * (float)t / 8.f;  w8[t]  = make_float2(cosf(a), sinf(a)); }
    if (t < NB_) sbins[t] = 0.f;
    if (t < 224) sx[t / 56][t % 56] = tmpF[bg * P_ + (r0 + t / 56) * 56 + (t % 56)];
    __syncthreads();
    if (t < 224) {     // stage 1
        int r = t / 56, j = t - r * 56;
        int n1 = j >> 3, k0 = j & 7;
        float sr = 0.f, si = 0.f; int i8 = 0;
        for (int n2 = 0; n2 < 8; ++n2) {
            float2 a = sx[r][7 * n2 + n1];
            float2 w = w8[i8];
            sr = fmaf(a.x, w.x, fmaf(-a.y, w.y, sr));
            si = fmaf(a.x, w.y, fmaf( a.y, w.x, si));
            i8 = (i8 + k0) & 7;
        }
        sT[r][j] = make_float2(sr, si);
    }
    __syncthreads();
    if (t < 224) {     // stage 2
        int r = t / 56, k = t - r * 56;
        int kw = r0 + r;
        float sr = 0.f, si = 0.f; int idx = 0;
        for (int n1 = 0; n1 < 7; ++n1) {
            float2 a = sT[r][(n1 << 3) + (k & 7)];
            float2 w = w56[idx];
            sr = fmaf(a.x, w.x, fmaf(-a.y, w.y, sr));
            si = fmaf(a.x, w.y, fmaf( a.y, w.x, si));
            idx += k; if (idx >= 56) idx -= 56;
        }
        if (kw <= 28) specS[bg * 29 * 56 + kw * 56 + k] = make_float2(sr, si);
        float amp = sqrtf(sr * sr + si * si);
        atomicAdd(&sbins[lab_of(k * 56 + kw)], amp);
    }
    __syncthreads();
    if (t < NB_) atomicAdd(&sums[bg * NB_ + t], sbins[t]);
    if (blk == 0) {
        __shared__ int s_cnt[NB_];
        if (t < NB_) s_cnt[t] = 0;
        __syncthreads();
        for (int p = t; p < P_; p += 256) atomicAdd(&s_cnt[lab_of(p)], 1);
        __syncthreads();
        if (t < NB_) inv_cnt[t] = 1.0f / (float)s_cnt[t];
    }
}

// Kernel 3: redundant per-block FC + fused Hermitian inverse (I1 over kh for
// kw=0..28, radix 7x8; then real half-spectrum I2 over kw) + plane min/max.
// One block per (bg, 4 h-rows). A[h][56-kw] = conj(A[h][kw]); A0, A28 real.
__global__ __launch_bounds__(256) void i12fc_kernel(const float2* __restrict__ specS,
                                                    const float* __restrict__ sums,
                                                    const float* __restrict__ inv_cnt,
                                                    const float* __restrict__ fc_w,
                                                    const float* __restrict__ fc_b,
                                                    float* __restrict__ nf,
                                                    unsigned* __restrict__ mnmx) {
    int blk = blockIdx.x, bg = blk / 14, h0 = (blk - bg * 14) * 4;
    int g = bg & 3;
    __shared__ float2 s_spec[29][57];    // [kw][kh], scaled by att
    __shared__ float2 sT[29][29];        // [kw][n1*4+r], 28 cols used
    __shared__ float2 sA[4][30];         // [r][kw 0..28]
    __shared__ float2 w56[56];
    __shared__ float2 w8[8];
    __shared__ float  s_pool[NB_], s_att[NB_];
    __shared__ float  red_mn[256], red_mx[256];
    int t = threadIdx.x;
    if (t < 56) { float a = TWO_PI * (float)t / 56.f; w56[t] = make_float2(cosf(a), sinf(a)); }
    if (t < 8)  { float a = TWO_PI * (float)t / 8.f;  w8[t]  = make_float2(cosf(a), sinf(a)); }
    if (t < NB_) s_pool[t] = sums[bg * NB_ + t] * inv_cnt[t];
    __syncthreads();
    if (t < NB_) {                       // FC + leaky relu (redundant per block)
        float acc = fc_b[g * NB_ + t];
        const float* wrow = &fc_w[(g * NB_ + t) * NB_];
        for (int n = 0; n < NB_; ++n) acc = fmaf(s_pool[n], wrow[n], acc);
        s_att[t] = acc >= 0.f ? acc : 0.01f * acc;
    }
    __syncthreads();
    // load scaled half-spectrum (kw 0..28)
    for (int i = t; i < 29 * 56; i += 256) {
        int kw = i / 56, kh = i - kw * 56;
        float2 v = specS[bg * 29 * 56 + i];
        float a = s_att[lab_of(kh * 56 + kw)];
        s_spec[kw][kh] = make_float2(v.x * a, v.y * a);
    }
    __syncthreads();
    // I1 stage 1: T[kw][n1][r] = sum_n2 s_spec[kw][7*n2+n1] * w8[(n2*k0)&7], k0=(h0+r)&7
    for (int i = t; i < 29 * 28; i += 256) {
        int kw = i / 28, j = i - kw * 28;
        int n1 = j >> 2, r = j & 3;
        int k0 = (h0 + r) & 7;
        float sr = 0.f, si = 0.f; int i8 = 0;
        for (int n2 = 0; n2 < 8; ++n2) {
            float2 a = s_spec[kw][7 * n2 + n1];
            float2 w = w8[i8];
            sr = fmaf(a.x, w.x, fmaf(-a.y, w.y, sr));
            si = fmaf(a.x, w.y, fmaf( a.y, w.x, si));
            i8 = (i8 + k0) & 7;
        }
        sT[kw][(n1 << 2) + r] = make_float2(sr, si);
    }
    __syncthreads();
    // I1 stage 2: A[r][kw] = sum_n1 sT[kw][n1*4+r] * w56[(n1*h)%56], h=h0+r
    if (t < 116) {
        int r = t / 29, kw = t - r * 29;
        int h = h0 + r;
        float sr = 0.f, si = 0.f; int idx = 0;
        for (int n1 = 0; n1 < 7; ++n1) {
            float2 a = sT[kw][(n1 << 2) + r];
            float2 w = w56[idx];
            sr = fmaf(a.x, w.x, fmaf(-a.y, w.y, sr));
            si = fmaf(a.x, w.y, fmaf( a.y, w.x, si));
            idx += h; if (idx >= 56) idx -= 56;
        }
        sA[r][kw] = make_float2(sr, si);
    }
    __syncthreads();
    // I2 (real, half-spectrum): nf[h][w] = (1/P)[A0 + (-1)^w A28 + 2 sum_{1..27} Re(A e^{i 2pi kw w/56})]
    float lmn = INFINITY, lmx = -INFINITY;
    if (t < 224) {
        int r = t / 56, w = t - r * 56;
        float acc = sA[r][0].x + ((w & 1) ? -sA[r][28].x : sA[r][28].x);
        int idx = w;
        for (int kw = 1; kw < 28; ++kw) {
            float2 a = sA[r][kw];
            float2 tw = w56[idx];
            acc = fmaf(2.f * a.x, tw.x, fmaf(-2.f * a.y, tw.y, acc));
            idx += w; if (idx >= 56) idx -= 56;
        }
        float v = acc * (1.0f / (float)P_);
        nf[bg * P_ + (h0 + r) * 56 + w] = v;
        lmn = v; lmx = v;
    }
    red_mn[t] = lmn; red_mx[t] = lmx;
    __syncthreads();
    for (int off = 128; off > 0; off >>= 1) {
        if (t < off) {
            red_mn[t] = fminf(red_mn[t], red_mn[t + off]);
            red_mx[t] = fmaxf(red_mx[t], red_mx[t + off]);
        }
        __syncthreads();
    }
    if (t == 0) {
        atomicMin(&mnmx[bg * 2 + 0], fkey(red_mn[0]));
        atomicMax(&mnmx[bg * 2 + 1], fkey(red_mx[0]));
    }
}

// Kernel 4: out = feature + gamma[c] * feature * attn_map, float4, nt stores.
__global__ __launch_bounds__(256) void final_kernel(const float* __restrict__ feature,
                                                    const float* __restrict__ gamma,
                                                    const float* __restrict__ nf,
                                                    const unsigned* __restrict__ mnmx,
                                                    float* __restrict__ out) {
    int i = blockIdx.x * 256 + threadIdx.x;      // over N4_ (exact)
    int b = i / (C_ * 784);
    int rem = i - b * (C_ * 784);
    int c = rem / 784;
    int p4 = rem - c * 784;
    int bg = (b << 2) | (c >> 6);
    float mn = fdec(mnmx[bg * 2 + 0]);
    float mx = fdec(mnmx[bg * 2 + 1]);
    float inv = 1.0f / (mx - mn);
    float4 f = ((const float4*)feature)[i];
    float4 v = ((const float4*)nf)[bg * 784 + p4];
    float gam = gamma[c];
    f4_t o;
    o.x = f.x + gam * f.x * ((v.x - mn) * inv);
    o.y = f.y + gam * f.y * ((v.y - mn) * inv);
    o.z = f.z + gam * f.z * ((v.z - mn) * inv);
    o.w = f.w + gam * f.w * ((v.w - mn) * inv);
    __builtin_nontemporal_store(o, ((f4_t*)out) + i);
}

extern "C" void kernel_launch(void* const* d_in, const int* in_sizes, int n_in,
                              void* d_out, int out_size, void* d_ws, size_t ws_size,
                              hipStream_t stream) {
    const float* feature = (const float*)d_in[0];
    const float* gamma   = (const float*)d_in[1];
    const float* fc_w    = (const float*)d_in[2];
    const float* fc_b    = (const float*)d_in[3];

    float* ws = (float*)d_ws;
    float2*   tmpF    = (float2*)ws;                // 401408 float2
    float2*   specS   = (float2*)(ws + 802816);     // 29*56*BG_ = 207872 float2
    float*    nf      = ws + 1218560;               // 401408
    float*    sums    = ws + 1619968;               // 3712
    float*    inv_cnt = ws + 1623680;               // 32
    unsigned* mnmx    = (unsigned*)(ws + 1623712);  // 256
    float*    out     = (float*)d_out;

    comp_f1_kernel<<<BG_ * 14, 256, 0, stream>>>(feature, tmpF, sums, mnmx);
    f2_kernel     <<<BG_ * 14, 256, 0, stream>>>(tmpF, specS, sums, inv_cnt);
    i12fc_kernel  <<<BG_ * 14, 256, 0, stream>>>(specS, sums, inv_cnt, fc_w, fc_b, nf, mnmx);
    final_kernel  <<<N4_ / 256, 256, 0, stream>>>(feature, gamma, nf, mnmx, out);
}

// Round 10
// 73.414 us; speedup vs baseline: 1.1304x; 1.1304x over previous
//
#include <hip/hip_runtime.h>
#include <math.h>

// Problem constants: B=32, C=256, H=W=56, group=4, d=1
constexpr int B_  = 32;
constexpr int C_  = 256;
constexpr int G_  = 4;
constexpr int K_  = 64;
constexpr int P_  = 3136;        // 56*56
constexpr int NB_ = 29;
constexpr int BG_ = 128;         // B*G
constexpr int CP_ = C_ * P_;
constexpr int N_  = B_ * CP_;
constexpr int N4_ = N_ / 4;
constexpr int HP_ = 29 * 56;     // 1624, half-plane points
constexpr float TWO_PI = 6.283185307179586f;

typedef float f4_t __attribute__((ext_vector_type(4)));   // native vec for nt-store

// Radial bin label in RAW (unshifted) coords, p = a*56 + b (symmetric in a,b
// and under a->56-a, b->56-b).
__device__ __forceinline__ int lab_of(int p) {
    int h = p / 56, w = p - h * 56;
    int hh = ((h + 28) % 56) - 28;
    int ww = ((w + 28) % 56) - 28;
    int r2 = hh * hh + ww * ww;
    int rf = (int)sqrtf((float)r2);
    while ((rf + 1) * (rf + 1) <= r2) ++rf;
    while (rf * rf > r2) --rf;
    if (rf > 28) rf = 28;
    return rf;
}

// Ordered-uint key for float atomic min/max.
__device__ __forceinline__ unsigned fkey(float f) {
    unsigned u = __float_as_uint(f);
    return (u & 0x80000000u) ? ~u : (u | 0x80000000u);
}
__device__ __forceinline__ float fdec(unsigned k) {
    return (k & 0x80000000u) ? __uint_as_float(k ^ 0x80000000u) : __uint_as_float(~k);
}

// ---------------------------------------------------------------------------
// Radix 7x8 over a 56-line: n = 7*n2 + n1,
//   X[k] = sum_{n1<7} e^{s 2pi i n1 k/56} * T[n1][k&7],
//   T[n1][k0] = sum_{n2<8} x[7*n2+n1] e^{s 2pi i n2 k0/8}
// ---------------------------------------------------------------------------

// Kernel 1: fused comp + row-DFT (F1), Hermitian half only (kw<=28).
// One block per (bg, 4 h-rows). tmpF[bg][kw][h], kw=0..28.
// rblk==0 re-inits sums/mnmx.
__global__ __launch_bounds__(256) void comp_f1_kernel(const float* __restrict__ feature,
                                                      float2* __restrict__ tmpF,
                                                      float* __restrict__ sums,
                                                      unsigned* __restrict__ mnmx) {
    int blk = blockIdx.x, bg = blk / 14, rblk = blk - bg * 14, r0 = rblk * 4;
    int b = bg >> 2, g = bg & 3;
    int t = threadIdx.x;
    __shared__ float  sx[4][57];
    __shared__ float2 stw[56];
    if (rblk == 0) {
        if (t < NB_) sums[bg * NB_ + t] = 0.f;
        else if (t == NB_)     mnmx[bg * 2]     = 0xFFFFFFFFu;
        else if (t == NB_ + 1) mnmx[bg * 2 + 1] = 0u;
    }
    if (t < 56) { float a = -TWO_PI * (float)t / 56.f; stw[t] = make_float2(cosf(a), sinf(a)); }
    if (t < 224) {
        const float* base = feature + (b * C_ + g * K_) * P_ + r0 * 56 + t;
        float sum = 0.f, mx = -INFINITY;
#pragma unroll 8
        for (int k = 0; k < K_; ++k) {
            float v = base[k * P_];
            sum += v;
            mx = fmaxf(mx, v);
        }
        sx[t / 56][t % 56] = sum * (1.f / 64.f) + mx;
    }
    __syncthreads();
    if (t < 116) {                    // 29 kw x 4 rows
        int r = t & 3, k = t >> 2;    // k = 0..28
        float sr = 0.f, si = 0.f; int idx = 0;
        for (int j = 0; j < 56; ++j) {
            float v = sx[r][j];
            float2 tw = stw[idx];
            sr = fmaf(v, tw.x, sr); si = fmaf(v, tw.y, si);
            idx += k; if (idx >= 56) idx -= 56;
        }
        tmpF[bg * HP_ + k * 56 + (r0 + r)] = make_float2(sr, si);
    }
}

// Kernel 2: F2 (col DFT over h, radix 7x8) on the kw half + radial bin sums
// (weight 2 for kw=1..27 mirrors). 8 blocks/plane x 4 kw-lines.
// Block 0 also computes inv_cnt (pure geometry).
__global__ __launch_bounds__(256) void f2_kernel(const float2* __restrict__ tmpF,
                                                 float2* __restrict__ specS,
                                                 float* __restrict__ sums,
                                                 float* __restrict__ inv_cnt) {
    int blk = blockIdx.x, bg = blk >> 3, kw0 = (blk & 7) * 4;
    __shared__ float2 sx[4][57];
    __shared__ float2 sT[4][57];
    __shared__ float2 w56[56];
    __shared__ float2 w8[8];
    __shared__ float  sbins[NB_];
    int t = threadIdx.x;
    if (t < 56) { float a = -TWO_PI * (float)t / 56.f; w56[t] = make_float2(cosf(a), sinf(a)); }
    if (t < 8)  { float a = -TWO_PI * (float)t / 8.f;  w8[t]  = make_float2(cosf(a), sinf(a)); }
    if (t < NB_) sbins[t] = 0.f;
    if (t < 224) {
        int r = t / 56, c = t - r * 56;
        if (kw0 + r <= 28) sx[r][c] = tmpF[bg * HP_ + (kw0 + r) * 56 + c];
    }
    __syncthreads();
    if (t < 224) {     // stage 1
        int r = t / 56, j = t - r * 56;
        int n1 = j >> 3, k0 = j & 7;
        float sr = 0.f, si = 0.f; int i8 = 0;
        for (int n2 = 0; n2 < 8; ++n2) {
            float2 a = sx[r][7 * n2 + n1];
            float2 w = w8[i8];
            sr = fmaf(a.x, w.x, fmaf(-a.y, w.y, sr));
            si = fmaf(a.x, w.y, fmaf( a.y, w.x, si));
            i8 = (i8 + k0) & 7;
        }
        sT[r][j] = make_float2(sr, si);
    }
    __syncthreads();
    if (t < 224) {     // stage 2
        int r = t / 56, k = t - r * 56;
        int kw = kw0 + r;
        if (kw <= 28) {
            float sr = 0.f, si = 0.f; int idx = 0;
            for (int n1 = 0; n1 < 7; ++n1) {
                float2 a = sT[r][(n1 << 3) + (k & 7)];
                float2 w = w56[idx];
                sr = fmaf(a.x, w.x, fmaf(-a.y, w.y, sr));
                si = fmaf(a.x, w.y, fmaf( a.y, w.x, si));
                idx += k; if (idx >= 56) idx -= 56;
            }
            specS[bg * HP_ + kw * 56 + k] = make_float2(sr, si);
            float amp = sqrtf(sr * sr + si * si);
            float wgt = (kw == 0 || kw == 28) ? 1.f : 2.f;
            atomicAdd(&sbins[lab_of(k * 56 + kw)], amp * wgt);
        }
    }
    __syncthreads();
    if (t < NB_) atomicAdd(&sums[bg * NB_ + t], sbins[t]);
    if (blk == 0) {
        __shared__ int s_cnt[NB_];
        if (t < NB_) s_cnt[t] = 0;
        __syncthreads();
        for (int p = t; p < P_; p += 256) atomicAdd(&s_cnt[lab_of(p)], 1);
        __syncthreads();
        if (t < NB_) inv_cnt[t] = 1.0f / (float)s_cnt[t];
    }
}

// Kernel 3: redundant per-block FC + I1 (inverse DFT over kh, radix 7x8) on
// the kw half. 8 blocks/plane x 4 kw-rows. A_s[bg][h][kw], kw=0..28.
__global__ __launch_bounds__(256) void i1fc_kernel(const float2* __restrict__ specS,
                                                   const float* __restrict__ sums,
                                                   const float* __restrict__ inv_cnt,
                                                   const float* __restrict__ fc_w,
                                                   const float* __restrict__ fc_b,
                                                   float2* __restrict__ A_s) {
    int blk = blockIdx.x, bg = blk >> 3, kw0 = (blk & 7) * 4;
    int g = bg & 3;
    __shared__ float2 sx[4][57];
    __shared__ float2 sT[4][57];
    __shared__ float2 w56[56];
    __shared__ float2 w8[8];
    __shared__ float  s_pool[NB_], s_att[NB_];
    int t = threadIdx.x;
    if (t < 56) { float a = TWO_PI * (float)t / 56.f; w56[t] = make_float2(cosf(a), sinf(a)); }
    if (t < 8)  { float a = TWO_PI * (float)t / 8.f;  w8[t]  = make_float2(cosf(a), sinf(a)); }
    if (t < NB_) s_pool[t] = sums[bg * NB_ + t] * inv_cnt[t];
    __syncthreads();
    if (t < NB_) {
        float acc = fc_b[g * NB_ + t];
        const float* wrow = &fc_w[(g * NB_ + t) * NB_];
        for (int n = 0; n < NB_; ++n) acc = fmaf(s_pool[n], wrow[n], acc);
        s_att[t] = acc >= 0.f ? acc : 0.01f * acc;
    }
    __syncthreads();
    if (t < 224) {     // load + scale 4 kw rows
        int r = t / 56, kh = t - r * 56;
        int kw = kw0 + r;
        if (kw <= 28) {
            float2 v = specS[bg * HP_ + kw * 56 + kh];
            float a = s_att[lab_of(kh * 56 + kw)];
            sx[r][kh] = make_float2(v.x * a, v.y * a);
        }
    }
    __syncthreads();
    if (t < 224) {     // stage 1
        int r = t / 56, j = t - r * 56;
        int n1 = j >> 3, k0 = j & 7;
        float sr = 0.f, si = 0.f; int i8 = 0;
        for (int n2 = 0; n2 < 8; ++n2) {
            float2 a = sx[r][7 * n2 + n1];
            float2 w = w8[i8];
            sr = fmaf(a.x, w.x, fmaf(-a.y, w.y, sr));
            si = fmaf(a.x, w.y, fmaf( a.y, w.x, si));
            i8 = (i8 + k0) & 7;
        }
        sT[r][j] = make_float2(sr, si);
    }
    __syncthreads();
    if (t < 224) {     // stage 2: output over h
        int r = t / 56, h = t - r * 56;
        int kw = kw0 + r;
        if (kw <= 28) {
            float sr = 0.f, si = 0.f; int idx = 0;
            for (int n1 = 0; n1 < 7; ++n1) {
                float2 a = sT[r][(n1 << 3) + (h & 7)];
                float2 w = w56[idx];
                sr = fmaf(a.x, w.x, fmaf(-a.y, w.y, sr));
                si = fmaf(a.x, w.y, fmaf( a.y, w.x, si));
                idx += h; if (idx >= 56) idx -= 56;
            }
            A_s[bg * HP_ + h * 29 + kw] = make_float2(sr, si);
        }
    }
}

// Kernel 4: I2 (inverse DFT over kw, radix 7x8, real part) + plane min/max.
// Block owns 4 h rows; loads the kw half, mirrors by conjugation in LDS.
__global__ __launch_bounds__(256) void i2_kernel(const float2* __restrict__ A_s,
                                                 float* __restrict__ nf,
                                                 unsigned* __restrict__ mnmx) {
    int blk = blockIdx.x, bg = blk / 14, h0 = (blk - bg * 14) * 4;
    __shared__ float2 sx[4][57];
    __shared__ float2 sT[4][57];
    __shared__ float2 w56[56];
    __shared__ float2 w8[8];
    __shared__ float  red_mn[256], red_mx[256];
    int t = threadIdx.x;
    if (t < 56) { float a = TWO_PI * (float)t / 56.f; w56[t] = make_float2(cosf(a), sinf(a)); }
    if (t < 8)  { float a = TWO_PI * (float)t / 8.f;  w8[t]  = make_float2(cosf(a), sinf(a)); }
    if (t < 116) {     // load 29 + mirror to 56 (conjugate)
        int r = t / 29, kw = t - r * 29;
        float2 v = A_s[bg * HP_ + (h0 + r) * 29 + kw];
        sx[r][kw] = v;
        if (kw >= 1 && kw <= 27) sx[r][56 - kw] = make_float2(v.x, -v.y);
    }
    __syncthreads();
    if (t < 224) {     // stage 1
        int r = t / 56, j = t - r * 56;
        int n1 = j >> 3, k0 = j & 7;
        float sr = 0.f, si = 0.f; int i8 = 0;
        for (int n2 = 0; n2 < 8; ++n2) {
            float2 a = sx[r][7 * n2 + n1];
            float2 w = w8[i8];
            sr = fmaf(a.x, w.x, fmaf(-a.y, w.y, sr));
            si = fmaf(a.x, w.y, fmaf( a.y, w.x, si));
            i8 = (i8 + k0) & 7;
        }
        sT[r][j] = make_float2(sr, si);
    }
    __syncthreads();
    float lmn = INFINITY, lmx = -INFINITY;
    if (t < 224) {     // stage 2, real part only
        int r = t / 56, w = t - r * 56;
        float sr = 0.f; int idx = 0;
        for (int n1 = 0; n1 < 7; ++n1) {
            float2 a = sT[r][(n1 << 3) + (w & 7)];
            float2 tw = w56[idx];
            sr = fmaf(a.x, tw.x, fmaf(-a.y, tw.y, sr));
            idx += w; if (idx >= 56) idx -= 56;
        }
        float v = sr * (1.0f / (float)P_);
        nf[bg * P_ + (h0 + r) * 56 + w] = v;
        lmn = v; lmx = v;
    }
    red_mn[t] = lmn; red_mx[t] = lmx;
    __syncthreads();
    for (int off = 128; off > 0; off >>= 1) {
        if (t < off) {
            red_mn[t] = fminf(red_mn[t], red_mn[t + off]);
            red_mx[t] = fmaxf(red_mx[t], red_mx[t + off]);
        }
        __syncthreads();
    }
    if (t == 0) {
        atomicMin(&mnmx[bg * 2 + 0], fkey(red_mn[0]));
        atomicMax(&mnmx[bg * 2 + 1], fkey(red_mx[0]));
    }
}

// Kernel 5: out = feature + gamma[c] * feature * attn_map, float4, nt stores.
__global__ __launch_bounds__(256) void final_kernel(const float* __restrict__ feature,
                                                    const float* __restrict__ gamma,
                                                    const float* __restrict__ nf,
                                                    const unsigned* __restrict__ mnmx,
                                                    float* __restrict__ out) {
    int i = blockIdx.x * 256 + threadIdx.x;      // over N4_ (exact)
    int b = i / (C_ * 784);
    int rem = i - b * (C_ * 784);
    int c = rem / 784;
    int p4 = rem - c * 784;
    int bg = (b << 2) | (c >> 6);
    float mn = fdec(mnmx[bg * 2 + 0]);
    float mx = fdec(mnmx[bg * 2 + 1]);
    float inv = 1.0f / (mx - mn);
    float4 f = ((const float4*)feature)[i];
    float4 v = ((const float4*)nf)[bg * 784 + p4];
    float gam = gamma[c];
    f4_t o;
    o.x = f.x + gam * f.x * ((v.x - mn) * inv);
    o.y = f.y + gam * f.y * ((v.y - mn) * inv);
    o.z = f.z + gam * f.z * ((v.z - mn) * inv);
    o.w = f.w + gam * f.w * ((v.w - mn) * inv);
    __builtin_nontemporal_store(o, ((f4_t*)out) + i);
}

extern "C" void kernel_launch(void* const* d_in, const int* in_sizes, int n_in,
                              void* d_out, int out_size, void* d_ws, size_t ws_size,
                              hipStream_t stream) {
    const float* feature = (const float*)d_in[0];
    const float* gamma   = (const float*)d_in[1];
    const float* fc_w    = (const float*)d_in[2];
    const float* fc_b    = (const float*)d_in[3];

    float* ws = (float*)d_ws;
    float2*   tmpF    = (float2*)ws;                // HP_*BG_ = 207872 float2
    float2*   specS   = (float2*)(ws + 415744);     // 207872 float2
    float*    nf      = ws + 831488;                // 401408
    float*    sums    = ws + 1232896;               // 3712
    float*    inv_cnt = ws + 1236608;               // 32
    unsigned* mnmx    = (unsigned*)(ws + 1236640);  // 256
    float2*   A_s     = tmpF;                       // reuse (tmpF dead after f2)
    float*    out     = (float*)d_out;

    comp_f1_kernel<<<BG_ * 14, 256, 0, stream>>>(feature, tmpF, sums, mnmx);
    f2_kernel     <<<BG_ * 8, 256, 0, stream>>>(tmpF, specS, sums, inv_cnt);
    i1fc_kernel   <<<BG_ * 8, 256, 0, stream>>>(specS, sums, inv_cnt, fc_w, fc_b, A_s);
    i2_kernel     <<<BG_ * 14, 256, 0, stream>>>(A_s, nf, mnmx);
    final_kernel  <<<N4_ / 256, 256, 0, stream>>>(feature, gamma, nf, mnmx, out);
}